// Round 1
// baseline (142.667 us; speedup 1.0000x reference)
//
#include <hip/hip_runtime.h>
#include <hip/hip_bf16.h>

#define T_DIM 256
#define B_DIM 128
#define I_DIM 512
#define H_DIM 1024

typedef __attribute__((ext_vector_type(4))) float f32x4;
typedef __attribute__((ext_vector_type(8))) short short8;  // 8 bf16 in 4 VGPRs

__device__ inline unsigned short f2bf(float f) {
    __hip_bfloat16 h = __float2bfloat16(f);  // RNE
    unsigned short u;
    __builtin_memcpy(&u, &h, sizeof(u));
    return u;
}

// C[m][n] = sum_k A[m][k] * B[n][k]  (+ bias terms per MODE), A,B f32 in global,
// converted to bf16 on the fly. Tile 128x128, BK=64, 256 threads (4 waves 2x2),
// 16x16x32 bf16 MFMA, XOR-swizzled LDS to kill ds_read_b128 bank conflicts.
//
// MODE 0: C[m][n] = dot + bias0[n] + bias1[n]                   (biasall build)
// MODE 1: v = relu(dot + bias0[(m&127)*N + n]); C[m][n] = v;
//         if m in last 128 rows also Clast[(m&127)*N + n] = v.  (main GEMM)
template <int MODE>
__global__ __launch_bounds__(256, 2) void gemm_bt(
    const float* __restrict__ A, const float* __restrict__ Bm,
    int M, int N, int K,
    const float* __restrict__ bias0, const float* __restrict__ bias1,
    float* __restrict__ C, float* __restrict__ Clast) {
    __shared__ unsigned short As[128 * 64];
    __shared__ unsigned short Bs[128 * 64];

    const int tid = threadIdx.x;
    const int wid = tid >> 6;
    const int lane = tid & 63;
    const int wr = wid >> 1, wc = wid & 1;
    const int lhi = lane >> 4;   // 0..3  (k-chunk of fragment)
    const int llo = lane & 15;   // row/col within fragment

    const int m0 = blockIdx.y * 128;
    const int n0 = blockIdx.x * 128;

    f32x4 acc[4][4] = {};

    for (int k0 = 0; k0 < K; k0 += 64) {
        if (k0) __syncthreads();
        // ---- stage A-tile and B-tile: 128x64 f32 -> bf16 LDS (swizzled) ----
        const float* Abase = A + (size_t)m0 * K + k0;
        const float* Bbase = Bm + (size_t)n0 * K + k0;
#pragma unroll
        for (int g = 0; g < 4; ++g) {
            int idx = tid + g * 256;
            int row = idx >> 3;
            int c8 = idx & 7;
            const float* src = Abase + (size_t)row * K + c8 * 8;
            f32x4 lo = *(const f32x4*)src;
            f32x4 hi = *(const f32x4*)(src + 4);
            union { unsigned short s[8]; short8 v; } pk;
#pragma unroll
            for (int j = 0; j < 4; ++j) pk.s[j] = f2bf(lo[j]);
#pragma unroll
            for (int j = 0; j < 4; ++j) pk.s[4 + j] = f2bf(hi[j]);
            int slot = c8 ^ (row & 7);
            *(short8*)&As[row * 64 + slot * 8] = pk.v;
        }
#pragma unroll
        for (int g = 0; g < 4; ++g) {
            int idx = tid + g * 256;
            int row = idx >> 3;
            int c8 = idx & 7;
            const float* src = Bbase + (size_t)row * K + c8 * 8;
            f32x4 lo = *(const f32x4*)src;
            f32x4 hi = *(const f32x4*)(src + 4);
            union { unsigned short s[8]; short8 v; } pk;
#pragma unroll
            for (int j = 0; j < 4; ++j) pk.s[j] = f2bf(lo[j]);
#pragma unroll
            for (int j = 0; j < 4; ++j) pk.s[4 + j] = f2bf(hi[j]);
            int slot = c8 ^ (row & 7);
            *(short8*)&Bs[row * 64 + slot * 8] = pk.v;
        }
        __syncthreads();

        // ---- MFMA on the 128x128x64 tile ----
#pragma unroll
        for (int ks = 0; ks < 2; ++ks) {
            short8 af[4], bfr[4];
#pragma unroll
            for (int mi = 0; mi < 4; ++mi) {
                int ar = wr * 64 + mi * 16 + llo;
                int slot = ((ks << 2) + lhi) ^ (ar & 7);
                af[mi] = *(const short8*)&As[ar * 64 + slot * 8];
            }
#pragma unroll
            for (int ni = 0; ni < 4; ++ni) {
                int br = wc * 64 + ni * 16 + llo;
                int slot = ((ks << 2) + lhi) ^ (br & 7);
                bfr[ni] = *(const short8*)&Bs[br * 64 + slot * 8];
            }
#pragma unroll
            for (int mi = 0; mi < 4; ++mi)
#pragma unroll
                for (int ni = 0; ni < 4; ++ni)
                    acc[mi][ni] = __builtin_amdgcn_mfma_f32_16x16x32_bf16(
                        af[mi], bfr[ni], acc[mi][ni], 0, 0, 0);
        }
    }

    // ---- epilogue ----
    const bool last_tile = (m0 == M - 128);
#pragma unroll
    for (int mi = 0; mi < 4; ++mi) {
#pragma unroll
        for (int ni = 0; ni < 4; ++ni) {
            int col = n0 + wc * 64 + ni * 16 + llo;
            int rowb = m0 + wr * 64 + mi * 16 + lhi * 4;
            if (MODE == 0) {
                float bsum = bias0[col] + bias1[col];
#pragma unroll
                for (int r = 0; r < 4; ++r)
                    C[(size_t)(rowb + r) * N + col] = acc[mi][ni][r] + bsum;
            } else {
#pragma unroll
                for (int r = 0; r < 4; ++r) {
                    int row = rowb + r;
                    float v = acc[mi][ni][r] + bias0[(row & 127) * N + col];
                    v = fmaxf(v, 0.0f);
                    C[(size_t)row * N + col] = v;
                    if (last_tile) Clast[(row & 127) * N + col] = v;
                }
            }
        }
    }
}

extern "C" void kernel_launch(void* const* d_in, const int* in_sizes, int n_in,
                              void* d_out, int out_size, void* d_ws, size_t ws_size,
                              hipStream_t stream) {
    const float* x = (const float*)d_in[0];       // (T,B,I)
    const float* hidden = (const float*)d_in[1];  // (B,H)
    const float* W_ih = (const float*)d_in[2];    // (H,I)
    const float* W_hh = (const float*)d_in[3];    // (H,H)
    const float* b_ih = (const float*)d_in[4];    // (H,)
    const float* b_hh = (const float*)d_in[5];    // (H,)

    float* out = (float*)d_out;                              // (T,B,H)
    float* out_last = out + (size_t)T_DIM * B_DIM * H_DIM;   // (B,H)
    float* biasall = (float*)d_ws;                           // (B,H) f32, 512 KB

    dim3 blk(256);
    // biasall[b][h] = hidden[b] . W_hh[h] + b_ih[h] + b_hh[h]
    gemm_bt<0><<<dim3(H_DIM / 128, B_DIM / 128), blk, 0, stream>>>(
        hidden, W_hh, B_DIM, H_DIM, H_DIM, b_ih, b_hh, biasall, nullptr);
    // out[m][h] = relu(x[m] . W_ih[h] + biasall[m&127][h]); + out[-1] copy
    gemm_bt<1><<<dim3(H_DIM / 128, (T_DIM * B_DIM) / 128), blk, 0, stream>>>(
        x, W_ih, T_DIM * B_DIM, H_DIM, I_DIM, biasall, nullptr, out, out_last);
}

// Round 2
// 115.679 us; speedup vs baseline: 1.2333x; 1.2333x over previous
//
#include <hip/hip_runtime.h>
#include <hip/hip_bf16.h>

#define T_DIM 256
#define B_DIM 128
#define I_DIM 512
#define H_DIM 1024

typedef __attribute__((ext_vector_type(4))) float f32x4;
typedef __attribute__((ext_vector_type(8))) short short8;  // 8 bf16 in 4 VGPRs

__device__ inline unsigned short f2bf(float f) {
    __hip_bfloat16 h = __float2bfloat16(f);  // RNE
    unsigned short u;
    __builtin_memcpy(&u, &h, sizeof(u));
    return u;
}

// C[m][n] = sum_k A[m][k] * B[n][k]  (+ bias terms per MODE). A,B f32 in global,
// converted to bf16 on the fly. Tile 128x128, BK=64, 256 threads (4 waves 2x2),
// 16x16x32 bf16 MFMA, XOR-swizzled LDS (no ds_read bank conflicts, verified 0
// in round 1). Round-2 additions: XCD-aware block swizzle (T1) + issue-early
// register prefetch pipeline (T14): global loads for tile k+1 are issued
// before the MFMA phase of tile k; the f32->bf16 convert + ds_write happen
// after the post-compute barrier, so HBM latency hides under MFMA.
//
// MODE 0: C[m][n] = dot + bias0[n] + bias1[n]                   (biasall build)
// MODE 1: v = relu(dot + bias0[(m&127)*N + n]); C[m][n] = v;
//         if m in last 128 rows also Clast[(m&127)*N + n] = v.  (main GEMM)
template <int MODE>
__global__ __launch_bounds__(256, 2) void gemm_bt(
    const float* __restrict__ A, const float* __restrict__ Bm,
    int M, int N, int K,
    const float* __restrict__ bias0, const float* __restrict__ bias1,
    float* __restrict__ C, float* __restrict__ Clast) {
    __shared__ unsigned short As[128 * 64];
    __shared__ unsigned short Bs[128 * 64];

    const int tid = threadIdx.x;
    const int wid = tid >> 6;
    const int lane = tid & 63;
    const int wr = wid >> 1, wc = wid & 1;
    const int lhi = lane >> 4;   // 0..3  (k-chunk of fragment)
    const int llo = lane & 15;   // row/col within fragment

    // --- XCD-aware swizzle (bijective when gridDim.x % 8 == 0) ---
    const int orig = blockIdx.x;
    const int nwg = gridDim.x;
    const int wg = (nwg > 8 && (nwg & 7) == 0)
                       ? ((orig & 7) * (nwg >> 3) + (orig >> 3))
                       : orig;
    const int m0 = (wg >> 3) * 128;   // m-tile
    const int n0 = (wg & 7) * 128;    // n-tile (8 n-tiles, N=1024)

    // --- staging geometry: thread loads rows srow + g*32, cols c8*8..c8*8+7 ---
    const int srow = tid >> 3;               // 0..31
    const int c8 = tid & 7;
    const int slot8 = (c8 ^ (srow & 7)) * 8; // g-invariant (g*32 keeps row&7)

    const float* Aptr = A + (size_t)(m0 + srow) * K + c8 * 8;
    const float* Bptr = Bm + (size_t)(n0 + srow) * K + c8 * 8;

    f32x4 pf[2][4][2];  // [A/B][g][lo/hi] — in-flight prefetch registers

    auto issue = [&](int k0) {
#pragma unroll
        for (int g = 0; g < 4; ++g) {
            const float* pa = Aptr + (size_t)g * 32 * K + k0;
            const float* pb = Bptr + (size_t)g * 32 * K + k0;
            pf[0][g][0] = *(const f32x4*)pa;
            pf[0][g][1] = *(const f32x4*)(pa + 4);
            pf[1][g][0] = *(const f32x4*)pb;
            pf[1][g][1] = *(const f32x4*)(pb + 4);
        }
    };
    auto write_lds = [&]() {
#pragma unroll
        for (int g = 0; g < 4; ++g) {
            union { unsigned short s[8]; short8 v; } pka, pkb;
#pragma unroll
            for (int j = 0; j < 4; ++j) {
                pka.s[j] = f2bf(pf[0][g][0][j]);
                pka.s[4 + j] = f2bf(pf[0][g][1][j]);
                pkb.s[j] = f2bf(pf[1][g][0][j]);
                pkb.s[4 + j] = f2bf(pf[1][g][1][j]);
            }
            *(short8*)&As[(srow + g * 32) * 64 + slot8] = pka.v;
            *(short8*)&Bs[(srow + g * 32) * 64 + slot8] = pkb.v;
        }
    };

    f32x4 acc[4][4] = {};

    auto compute = [&]() {
#pragma unroll
        for (int ks = 0; ks < 2; ++ks) {
            short8 af[4], bfr[4];
#pragma unroll
            for (int mi = 0; mi < 4; ++mi) {
                int ar = wr * 64 + mi * 16 + llo;
                int slot = ((ks << 2) + lhi) ^ (ar & 7);
                af[mi] = *(const short8*)&As[ar * 64 + slot * 8];
            }
#pragma unroll
            for (int ni = 0; ni < 4; ++ni) {
                int br = wc * 64 + ni * 16 + llo;
                int slot = ((ks << 2) + lhi) ^ (br & 7);
                bfr[ni] = *(const short8*)&Bs[br * 64 + slot * 8];
            }
#pragma unroll
            for (int mi = 0; mi < 4; ++mi)
#pragma unroll
                for (int ni = 0; ni < 4; ++ni)
                    acc[mi][ni] = __builtin_amdgcn_mfma_f32_16x16x32_bf16(
                        af[mi], bfr[ni], acc[mi][ni], 0, 0, 0);
        }
    };

    // --- pipelined main loop ---
    issue(0);
    write_lds();        // waits vmcnt implicitly at first use
    __syncthreads();
    for (int k0 = 64; k0 < K; k0 += 64) {
        issue(k0);      // prefetch next tile (in flight during compute)
        compute();      // MFMA on current LDS tile
        __syncthreads();
        write_lds();    // convert + store prefetched tile
        __syncthreads();
    }
    compute();

    // ---- epilogue ----
    const bool last_tile = (m0 == M - 128);
#pragma unroll
    for (int mi = 0; mi < 4; ++mi) {
#pragma unroll
        for (int ni = 0; ni < 4; ++ni) {
            int col = n0 + wc * 64 + ni * 16 + llo;
            int rowb = m0 + wr * 64 + mi * 16 + lhi * 4;
            if (MODE == 0) {
                float bsum = bias0[col] + bias1[col];
#pragma unroll
                for (int r = 0; r < 4; ++r)
                    C[(size_t)(rowb + r) * N + col] = acc[mi][ni][r] + bsum;
            } else {
#pragma unroll
                for (int r = 0; r < 4; ++r) {
                    int row = rowb + r;
                    float v = acc[mi][ni][r] + bias0[(row & 127) * N + col];
                    v = fmaxf(v, 0.0f);
                    C[(size_t)row * N + col] = v;
                    if (last_tile) Clast[(row & 127) * N + col] = v;
                }
            }
        }
    }
}

extern "C" void kernel_launch(void* const* d_in, const int* in_sizes, int n_in,
                              void* d_out, int out_size, void* d_ws, size_t ws_size,
                              hipStream_t stream) {
    const float* x = (const float*)d_in[0];       // (T,B,I)
    const float* hidden = (const float*)d_in[1];  // (B,H)
    const float* W_ih = (const float*)d_in[2];    // (H,I)
    const float* W_hh = (const float*)d_in[3];    // (H,H)
    const float* b_ih = (const float*)d_in[4];    // (H,)
    const float* b_hh = (const float*)d_in[5];    // (H,)

    float* out = (float*)d_out;                              // (T,B,H)
    float* out_last = out + (size_t)T_DIM * B_DIM * H_DIM;   // (B,H)
    float* biasall = (float*)d_ws;                           // (B,H) f32, 512 KB

    // biasall[b][h] = hidden[b] . W_hh[h] + b_ih[h] + b_hh[h]
    gemm_bt<0><<<dim3(H_DIM / 128), dim3(256), 0, stream>>>(
        hidden, W_hh, B_DIM, H_DIM, H_DIM, b_ih, b_hh, biasall, nullptr);
    // out[m][h] = relu(x[m] . W_ih[h] + biasall[m&127][h]); + out[-1] copy
    gemm_bt<1><<<dim3((T_DIM * B_DIM) / 128 * (H_DIM / 128)), dim3(256), 0, stream>>>(
        x, W_ih, T_DIM * B_DIM, H_DIM, I_DIM, biasall, nullptr, out, out_last);
}

// Round 3
// 109.929 us; speedup vs baseline: 1.2978x; 1.0523x over previous
//
#include <hip/hip_runtime.h>
#include <hip/hip_bf16.h>
#include <stdint.h>

#define T_DIM 256
#define B_DIM 128
#define I_DIM 512
#define H_DIM 1024
#define M_DIM (T_DIM * B_DIM)

typedef __attribute__((ext_vector_type(4))) float f32x4;
typedef __attribute__((ext_vector_type(8))) short short8;  // 8 bf16 in 4 VGPRs

__device__ inline unsigned short f2bf(float f) {
    __hip_bfloat16 h = __float2bfloat16(f);  // RNE
    unsigned short u;
    __builtin_memcpy(&u, &h, sizeof(u));
    return u;
}

// async 16B global -> LDS (direct, no VGPR round trip). dest = wave-uniform
// base + lane*16, so LDS layout must be lane-linear; swizzle is applied on
// the GLOBAL source address (rule: both-sides-or-neither, same involution).
__device__ inline void gload_lds16(const void* g, void* l) {
    __builtin_amdgcn_global_load_lds(
        (const __attribute__((address_space(1))) uint32_t*)g,
        (__attribute__((address_space(3))) uint32_t*)l, 16, 0, 0);
}

// ---------------------------------------------------------------------------
// pack_W: W_ih (H,I) f32 -> bf16, re-tiled per (n_tile, k_step) into the exact
// swizzled 128x64 LDS image gemm_main wants. Image elem (r, slot s, 8 bf16)
// holds W granule g = s ^ (r&7); gemm reads granule g at slot g ^ (r&7).
// 65536 granules total, one per thread.
// ---------------------------------------------------------------------------
__global__ void pack_W(const float* __restrict__ W, unsigned short* __restrict__ Wp) {
    int id = blockIdx.x * 256 + threadIdx.x;   // 0..65535
    int s = id & 7;
    int r = (id >> 3) & 127;
    int kst = (id >> 10) & 7;
    int nt = id >> 13;
    int srcg = s ^ (r & 7);
    const float* src = W + (size_t)(nt * 128 + r) * I_DIM + kst * 64 + srcg * 8;
    f32x4 lo = *(const f32x4*)src;
    f32x4 hi = *(const f32x4*)(src + 4);
    union { unsigned short us[8]; short8 v; } pk;
#pragma unroll
    for (int j = 0; j < 4; ++j) { pk.us[j] = f2bf(lo[j]); pk.us[4 + j] = f2bf(hi[j]); }
    *(short8*)(Wp + (size_t)id * 8) = pk.v;
}

// ---------------------------------------------------------------------------
// Main GEMM: out[m][h] = relu(x[m].W_ih[h] + biasall[m&127][h]), m = t*128+b.
// 128x128 tile, BK=64, 4 waves (2x2), 16x16x32 bf16 MFMA.
// A (x, f32) staged via global_load_lds with pre-swizzled global source
// (granule ^= row&15 within the 256B row); converted f32->bf16 at fragment
// load (VALU overlaps MFMA across waves). B staged via linear global_load_lds
// from the pre-packed swizzled image. LDS 48 KB -> 3 blocks/CU.
// ---------------------------------------------------------------------------
__global__ __launch_bounds__(256, 3) void gemm_main(
    const float* __restrict__ X, const unsigned short* __restrict__ Wp,
    const float* __restrict__ biasall, float* __restrict__ C,
    float* __restrict__ Clast) {
    __shared__ float Asf[128 * 64];           // 32 KB, granule-swizzled
    __shared__ unsigned short Bsb[128 * 64];  // 16 KB, granule-swizzled

    const int tid = threadIdx.x;
    const int lane = tid & 63;
    const int wid = tid >> 6;
    const int wr = wid >> 1, wc = wid & 1;
    const int llo = lane & 15, lhi = lane >> 4;

    // XCD-aware swizzle (gridDim.x = 2048, divisible by 8)
    const int orig = blockIdx.x;
    const int nwg = gridDim.x;
    const int wg = ((orig & 7) * (nwg >> 3)) + (orig >> 3);
    const int mt = wg >> 3;
    const int nt = wg & 7;
    const int m0 = mt * 128;
    const int n0 = nt * 128;

    // A staging geometry: issue g covers rows g*16+(tid>>4), slot tid&15.
    // Slot s holds global granule s ^ (row&15); row&15 == tid>>4, g-invariant.
    const int arow_l = tid >> 4;  // 0..15
    const int csrc = (tid & 15) ^ arow_l;
    const float* Abase = X + (size_t)(m0 + arow_l) * I_DIM + csrc * 4;
    const unsigned short* Bbase = Wp + (size_t)nt * 8 * 8192 + (size_t)tid * 8;

    f32x4 acc[4][4] = {};

#pragma unroll
    for (int kst = 0; kst < I_DIM / 64; ++kst) {
        if (kst) __syncthreads();  // prior compute done before overwrite
        // stage A: 128x64 f32 = 32 KB, 8 x 16B per thread
        const float* asrc = Abase + kst * 64;
#pragma unroll
        for (int g = 0; g < 8; ++g)
            gload_lds16(asrc + (size_t)g * 16 * I_DIM,
                        (char*)Asf + (g * 256 + tid) * 16);
        // stage B: 16 KB pre-swizzled image, 4 x 16B per thread, fully linear
        const unsigned short* bsrc = Bbase + kst * 8192;
#pragma unroll
        for (int g = 0; g < 4; ++g)
            gload_lds16(bsrc + g * 2048, (char*)Bsb + (g * 256 + tid) * 16);
        __syncthreads();  // drains vmcnt(0) + barrier

#pragma unroll
        for (int ks = 0; ks < 2; ++ks) {
            short8 af[4], bfv[4];
#pragma unroll
            for (int mi = 0; mi < 4; ++mi) {
                int ar = wr * 64 + mi * 16 + llo;
                int g0 = ks * 8 + lhi * 2;
                f32x4 a0 = *(const f32x4*)&Asf[ar * 64 + ((g0 ^ (ar & 15)) << 2)];
                f32x4 a1 = *(const f32x4*)&Asf[ar * 64 + (((g0 + 1) ^ (ar & 15)) << 2)];
                union { unsigned short s[8]; short8 v; } pk;
#pragma unroll
                for (int j = 0; j < 4; ++j) {
                    pk.s[j] = f2bf(a0[j]);
                    pk.s[4 + j] = f2bf(a1[j]);
                }
                af[mi] = pk.v;
            }
#pragma unroll
            for (int ni = 0; ni < 4; ++ni) {
                int br = wc * 64 + ni * 16 + llo;
                int g = ks * 4 + lhi;
                bfv[ni] = *(const short8*)&Bsb[br * 64 + ((g ^ (br & 7)) << 3)];
            }
#pragma unroll
            for (int mi = 0; mi < 4; ++mi)
#pragma unroll
                for (int ni = 0; ni < 4; ++ni)
                    acc[mi][ni] = __builtin_amdgcn_mfma_f32_16x16x32_bf16(
                        af[mi], bfv[ni], acc[mi][ni], 0, 0, 0);
        }
    }

    // epilogue: bias + relu + store (+ out_last copy on final m-tile)
    const bool last_tile = (m0 == M_DIM - 128);
#pragma unroll
    for (int mi = 0; mi < 4; ++mi) {
#pragma unroll
        for (int ni = 0; ni < 4; ++ni) {
            int col = n0 + wc * 64 + ni * 16 + llo;
            int rowb = m0 + wr * 64 + mi * 16 + lhi * 4;
#pragma unroll
            for (int r = 0; r < 4; ++r) {
                int row = rowb + r;
                float v = acc[mi][ni][r] + biasall[(row & 127) * H_DIM + col];
                v = fmaxf(v, 0.0f);
                C[(size_t)row * H_DIM + col] = v;
                if (last_tile) Clast[(row & 127) * H_DIM + col] = v;
            }
        }
    }
}

// ---------------------------------------------------------------------------
// Legacy reg-staged kernel: MODE 0 builds biasall (tiny GEMM); MODE 1 is the
// known-correct fallback main GEMM if ws is too small for the packed-W path.
// ---------------------------------------------------------------------------
template <int MODE>
__global__ __launch_bounds__(256, 2) void gemm_bt(
    const float* __restrict__ A, const float* __restrict__ Bm,
    int M, int N, int K,
    const float* __restrict__ bias0, const float* __restrict__ bias1,
    float* __restrict__ C, float* __restrict__ Clast) {
    __shared__ unsigned short As[128 * 64];
    __shared__ unsigned short Bs[128 * 64];

    const int tid = threadIdx.x;
    const int wid = tid >> 6;
    const int lane = tid & 63;
    const int wr = wid >> 1, wc = wid & 1;
    const int lhi = lane >> 4;
    const int llo = lane & 15;

    const int orig = blockIdx.x;
    const int nwg = gridDim.x;
    const int wg = (nwg > 8 && (nwg & 7) == 0)
                       ? ((orig & 7) * (nwg >> 3) + (orig >> 3))
                       : orig;
    const int m0 = (wg >> 3) * 128;
    const int n0 = (wg & 7) * 128;

    const int srow = tid >> 3;
    const int c8 = tid & 7;
    const int slot8 = (c8 ^ (srow & 7)) * 8;

    const float* Aptr = A + (size_t)(m0 + srow) * K + c8 * 8;
    const float* Bptr = Bm + (size_t)(n0 + srow) * K + c8 * 8;

    f32x4 pf[2][4][2];

    auto issue = [&](int k0) {
#pragma unroll
        for (int g = 0; g < 4; ++g) {
            const float* pa = Aptr + (size_t)g * 32 * K + k0;
            const float* pb = Bptr + (size_t)g * 32 * K + k0;
            pf[0][g][0] = *(const f32x4*)pa;
            pf[0][g][1] = *(const f32x4*)(pa + 4);
            pf[1][g][0] = *(const f32x4*)pb;
            pf[1][g][1] = *(const f32x4*)(pb + 4);
        }
    };
    auto write_lds = [&]() {
#pragma unroll
        for (int g = 0; g < 4; ++g) {
            union { unsigned short s[8]; short8 v; } pka, pkb;
#pragma unroll
            for (int j = 0; j < 4; ++j) {
                pka.s[j] = f2bf(pf[0][g][0][j]);
                pka.s[4 + j] = f2bf(pf[0][g][1][j]);
                pkb.s[j] = f2bf(pf[1][g][0][j]);
                pkb.s[4 + j] = f2bf(pf[1][g][1][j]);
            }
            *(short8*)&As[(srow + g * 32) * 64 + slot8] = pka.v;
            *(short8*)&Bs[(srow + g * 32) * 64 + slot8] = pkb.v;
        }
    };

    f32x4 acc[4][4] = {};

    auto compute = [&]() {
#pragma unroll
        for (int ks = 0; ks < 2; ++ks) {
            short8 af[4], bfr[4];
#pragma unroll
            for (int mi = 0; mi < 4; ++mi) {
                int ar = wr * 64 + mi * 16 + llo;
                int slot = ((ks << 2) + lhi) ^ (ar & 7);
                af[mi] = *(const short8*)&As[ar * 64 + slot * 8];
            }
#pragma unroll
            for (int ni = 0; ni < 4; ++ni) {
                int br = wc * 64 + ni * 16 + llo;
                int slot = ((ks << 2) + lhi) ^ (br & 7);
                bfr[ni] = *(const short8*)&Bs[br * 64 + slot * 8];
            }
#pragma unroll
            for (int mi = 0; mi < 4; ++mi)
#pragma unroll
                for (int ni = 0; ni < 4; ++ni)
                    acc[mi][ni] = __builtin_amdgcn_mfma_f32_16x16x32_bf16(
                        af[mi], bfr[ni], acc[mi][ni], 0, 0, 0);
        }
    };

    issue(0);
    write_lds();
    __syncthreads();
    for (int k0 = 64; k0 < K; k0 += 64) {
        issue(k0);
        compute();
        __syncthreads();
        write_lds();
        __syncthreads();
    }
    compute();

    const bool last_tile = (m0 == M - 128);
#pragma unroll
    for (int mi = 0; mi < 4; ++mi) {
#pragma unroll
        for (int ni = 0; ni < 4; ++ni) {
            int col = n0 + wc * 64 + ni * 16 + llo;
            int rowb = m0 + wr * 64 + mi * 16 + lhi * 4;
            if (MODE == 0) {
                float bsum = bias0[col] + bias1[col];
#pragma unroll
                for (int r = 0; r < 4; ++r)
                    C[(size_t)(rowb + r) * N + col] = acc[mi][ni][r] + bsum;
            } else {
#pragma unroll
                for (int r = 0; r < 4; ++r) {
                    int row = rowb + r;
                    float v = acc[mi][ni][r] + bias0[(row & 127) * N + col];
                    v = fmaxf(v, 0.0f);
                    C[(size_t)row * N + col] = v;
                    if (last_tile) Clast[(row & 127) * N + col] = v;
                }
            }
        }
    }
}

extern "C" void kernel_launch(void* const* d_in, const int* in_sizes, int n_in,
                              void* d_out, int out_size, void* d_ws, size_t ws_size,
                              hipStream_t stream) {
    const float* x = (const float*)d_in[0];       // (T,B,I)
    const float* hidden = (const float*)d_in[1];  // (B,H)
    const float* W_ih = (const float*)d_in[2];    // (H,I)
    const float* W_hh = (const float*)d_in[3];    // (H,H)
    const float* b_ih = (const float*)d_in[4];    // (H,)
    const float* b_hh = (const float*)d_in[5];    // (H,)

    float* out = (float*)d_out;                              // (T,B,H)
    float* out_last = out + (size_t)T_DIM * B_DIM * H_DIM;   // (B,H)

    // ws layout: [0, 512K) biasall f32 ; [512K, 1.5M) packed W bf16
    float* biasall = (float*)d_ws;
    unsigned short* Wp = (unsigned short*)((char*)d_ws + 512 * 1024);
    const size_t ws_need = 512 * 1024 + (size_t)H_DIM * I_DIM * 2;

    // biasall[b][h] = hidden[b] . W_hh[h] + b_ih[h] + b_hh[h]
    gemm_bt<0><<<dim3(H_DIM / 128), dim3(256), 0, stream>>>(
        hidden, W_hh, B_DIM, H_DIM, H_DIM, b_ih, b_hh, biasall, nullptr);

    if (ws_size >= ws_need) {
        pack_W<<<dim3(H_DIM * I_DIM / 8 / 256), dim3(256), 0, stream>>>(W_ih, Wp);
        gemm_main<<<dim3(M_DIM / 128 * (H_DIM / 128)), dim3(256), 0, stream>>>(
            x, Wp, biasall, out, out_last);
    } else {
        gemm_bt<1><<<dim3(M_DIM / 128 * (H_DIM / 128)), dim3(256), 0, stream>>>(
            x, W_ih, M_DIM, H_DIM, I_DIM, biasall, nullptr, out, out_last);
    }
}